// Round 9
// baseline (1049.808 us; speedup 1.0000x reference)
//
#include <hip/hip_runtime.h>
#include <hip/hip_bf16.h>

// Problem constants (B=4, V=4096, D=256, H=4, Dh=64, KNN=10, TOPK=4, HID=64)
#define VV 4096
#define DDIM 256
#define KNN_K 10
#define TK 4

// fp32 helpers that forbid compiler contraction (bit-faithful np mimicry)
__device__ __forceinline__ float f_sq3(float x, float y, float z) {
    // np: sum(coo*coo, -1) = ((x*x + y*y) + z*z), each op rounded
    return __fadd_rn(__fadd_rn(__fmul_rn(x, x), __fmul_rn(y, y)), __fmul_rn(z, z));
}
__device__ __forceinline__ float f_dot3(float ax, float ay, float az,
                                        float bx, float by, float bz) {
    // OpenBLAS sgemm k=3 microkernel: ascending-k FMA chain, acc starts at 0
    float d = __fmul_rn(ax, bx);          // == fma(ax,bx,0)
    d = __fmaf_rn(ay, by, d);
    d = __fmaf_rn(az, bz, d);
    return d;
}

// ---------------------------------------------------------------------------
// Fully fused, shuffle-free, zero global scratch. All selection math is
// bit-faithful float32 (np reference mimicry); magnitudes fp32.
// One block (256 threads) per voxel.
// ---------------------------------------------------------------------------
__global__ void __launch_bounds__(256) fused_voxel_attn(
    const float* __restrict__ tok,
    const float* __restrict__ coords,
    const float* __restrict__ W1,
    const float* __restrict__ b1,
    const float* __restrict__ W2,
    const float* __restrict__ Wq, const float* __restrict__ bq,
    const float* __restrict__ Wk, const float* __restrict__ bk,
    const float* __restrict__ Wv, const float* __restrict__ bv,
    const float* __restrict__ Wo, const float* __restrict__ bo,
    float* __restrict__ out, int out_size)
{
    const int q    = blockIdx.x;       // 0..16383
    const int b    = q >> 12;
    const int v    = q & 4095;
    const int base = q & ~4095;
    const int tid  = threadIdx.x;
    const float* cb = coords + (size_t)b * VV * 3;

    __shared__ float  sval[256];
    __shared__ int    sidx[256];
    __shared__ int    sKnn[KNN_K];
    __shared__ int    sSel[TK];
    __shared__ float  sTokA[DDIM];
    __shared__ float  sTokN[KNN_K][DDIM];
    __shared__ float  sAH[64];           // anchor-prefix partial sums (fp32 chain)
    __shared__ float  sHid[KNN_K][64];   // relu'd hidden units
    __shared__ float  sSc[KNN_K];
    __shared__ float  sP[TK][256];       // per-(slot,tid) QK products
    __shared__ float  sAtt[4][TK];       // [head][slot]
    __shared__ float  sO[DDIM];

    // ---------------- Phase A: KNN, faithful fp32 d2 ----------------
    const float qx = cb[v * 3 + 0];
    const float qy = cb[v * 3 + 1];
    const float qz = cb[v * 3 + 2];
    const float sqq = f_sq3(qx, qy, qz);

    float d2[16];
    #pragma unroll
    for (int i = 0; i < 16; i++) {
        int j = tid + i * 256;
        float xj = cb[j * 3 + 0], yj = cb[j * 3 + 1], zj = cb[j * 3 + 2];
        float sqj = f_sq3(xj, yj, zj);
        float dt  = f_dot3(qx, qy, qz, xj, yj, zj);
        // d2 = (sq_i + sq_j) - 2*dot, each op rounded (2*dot exact)
        d2[i] = __fsub_rn(__fadd_rn(sqq, sqj), __fmul_rn(2.0f, dt));
    }

    unsigned used = 0;
    for (int it = 0; it < 11; it++) {
        float best = 3.4e38f;
        int bi = 0x7fffffff;
        #pragma unroll
        for (int i = 0; i < 16; i++) {
            if (used & (1u << i)) continue;
            if (d2[i] < best) { best = d2[i]; bi = tid + i * 256; }  // strict < keeps lowest idx
        }
        sval[tid] = best;
        sidx[tid] = bi;
        __syncthreads();
        for (int s = 128; s > 0; s >>= 1) {
            if (tid < s) {
                float v2 = sval[tid + s];
                int   i2 = sidx[tid + s];
                if (v2 < sval[tid] || (v2 == sval[tid] && i2 < sidx[tid])) {
                    sval[tid] = v2; sidx[tid] = i2;
                }
            }
            __syncthreads();
        }
        int w = sidx[0] & 4095;   // clamp: pathological data cannot drive OOB
        __syncthreads();          // all threads read winner before next-iter overwrite
        if (it >= 1 && tid == 0) sKnn[it - 1] = w;
        if ((w & 255) == tid) used |= 1u << (w >> 8);
    }
    __syncthreads();        // publish sKnn

    // ---------------- Phase B: score MLP, faithful fp32 ----------------
    sTokA[tid] = tok[(size_t)q * DDIM + tid];
    for (int nb = 0; nb < KNN_K; nb++)
        sTokN[nb][tid] = tok[(size_t)(base + sKnn[nb]) * DDIM + tid];
    __syncthreads();

    if (tid < 64) {   // anchor prefix of the 515-term chain (identical rounding for all nb)
        float a = 0.0f;
        for (int k = 0; k < 256; k++)
            a = __fmaf_rn(sTokA[k], W1[k * 64 + tid], a);
        sAH[tid] = a;
    }
    __syncthreads();

    // per-(nb,h): continue the chain: neighbor 256 terms, rel 3 terms, +b1, relu
    for (int idx = tid; idx < KNN_K * 64; idx += 256) {
        int nb = idx >> 6;
        int h  = idx & 63;
        float acc = sAH[h];
        const float* tn = sTokN[nb];
        for (int k = 0; k < 256; k++)
            acc = __fmaf_rn(tn[k], W1[(256 + k) * 64 + h], acc);
        #pragma unroll
        for (int c = 0; c < 3; c++) {
            float rel = __fsub_rn(cb[sKnn[nb] * 3 + c], cb[v * 3 + c]);
            acc = __fmaf_rn(rel, W1[(512 + c) * 64 + h], acc);
        }
        float hid = __fadd_rn(acc, b1[h]);
        sHid[nb][h] = hid > 0.0f ? hid : 0.0f;
    }
    __syncthreads();

    if (tid < KNN_K) {    // @ W2: ascending-h fp32 FMA chain (k=64 sgemm)
        float s = 0.0f;
        for (int h = 0; h < 64; h++)
            s = __fmaf_rn(sHid[tid][h], W2[h], s);
        sSc[tid] = s;     // b2 omitted: softmax/top-k invariant
    }
    __syncthreads();

    if (tid == 0) {       // stable top-4 on sc (monotone proxy for softmax aw)
        unsigned um = 0;
        #pragma unroll
        for (int s = 0; s < TK; s++) {
            float best = -3.4e38f;
            int bj = 0;
            for (int jj = 0; jj < KNN_K; jj++) {
                if (um & (1u << jj)) continue;
                if (sSc[jj] > best) { best = sSc[jj]; bj = jj; }  // strict > => earliest slot on ties
            }
            um |= 1u << bj;
            sSel[s] = bj;
        }
    }
    __syncthreads();

    // ---------------- Phase C: attention (fp32) + Wo ----------------
    int ss[TK];
    float k_acc[TK], v_acc[TK];
    #pragma unroll
    for (int s = 0; s < TK; s++) {
        ss[s] = sSel[s];
        k_acc[s] = bk[tid];
        v_acc[s] = bv[tid];
    }
    float q_acc = bq[tid];

    for (int k = 0; k < 256; k++) {
        float wq = Wq[k * 256 + tid];
        float wk = Wk[k * 256 + tid];
        float wv = Wv[k * 256 + tid];
        q_acc += sTokA[k] * wq;
        #pragma unroll
        for (int s = 0; s < TK; s++) {
            float x = sTokN[ss[s]][k];
            k_acc[s] += x * wk;
            v_acc[s] += x * wv;
        }
    }

    #pragma unroll
    for (int s = 0; s < TK; s++) sP[s][tid] = q_acc * k_acc[s];
    __syncthreads();

    if (tid < 16) {       // h = tid>>2, s = tid&3: serial sum over 64 dh
        int h = tid >> 2, s = tid & 3;
        float p = 0.0f;
        for (int d = 0; d < 64; d++) p += sP[s][h * 64 + d];
        sAtt[h][s] = p * 0.125f;   // 1/sqrt(64)
    }
    __syncthreads();

    const int hh = tid >> 6;
    float a0 = sAtt[hh][0], a1 = sAtt[hh][1], a2 = sAtt[hh][2], a3 = sAtt[hh][3];
    float mx  = fmaxf(fmaxf(a0, a1), fmaxf(a2, a3));
    float e0 = expf(a0 - mx), e1 = expf(a1 - mx), e2 = expf(a2 - mx), e3 = expf(a3 - mx);
    float inv = 1.0f / (e0 + e1 + e2 + e3);
    float o = (e0 * v_acc[0] + e1 * v_acc[1] + e2 * v_acc[2] + e3 * v_acc[3]) * inv;

    sO[tid] = o;
    __syncthreads();

    float a = bo[tid];
    for (int e = 0; e < 256; e++) a += sO[e] * Wo[e * 256 + tid];
    int oidx = q * DDIM + tid;
    if (oidx < out_size)
        out[oidx] = a;
}

// ---------------------------------------------------------------------------
// Launcher: ABI-bilingual ordered size-walk (worked in round 8; unchanged).
// Incomplete match -> launch nothing (clean failure). d_ws unused.
// ---------------------------------------------------------------------------
extern "C" void kernel_launch(void* const* d_in, const int* in_sizes, int n_in,
                              void* d_out, int out_size, void* d_ws, size_t ws_size,
                              hipStream_t stream)
{
    (void)d_ws; (void)ws_size;

    const long long want[13] = {4194304LL, 49152LL, 32960LL, 64LL, 64LL,
                                65536LL, 256LL, 65536LL, 256LL,
                                65536LL, 256LL, 65536LL, 256LL};
    int idx[13];
    const int n = n_in;

    const long long* s64 = (const long long*)(const void*)in_sizes;
    const int*       s32 = in_sizes;

    bool ok = false;

    if (n >= 13 && s64[0] == want[0]) {   // int64 interpretation (gated)
        ok = true;
        int walk = 0;
        for (int t = 0; t < 13; t++) {
            int f = -1;
            for (int i = walk; i < n; i++) {
                if (s64[i] == want[t]) { f = i; break; }
            }
            if (f < 0) { ok = false; break; }
            idx[t] = f; walk = f + 1;
        }
    }

    if (!ok) {                            // int32 interpretation
        ok = true;
        int walk = 0;
        for (int t = 0; t < 13; t++) {
            int f = -1;
            for (int i = walk; i < n; i++) {
                if ((long long)s32[i] == want[t]) { f = i; break; }
            }
            if (f < 0) { ok = false; break; }
            idx[t] = f; walk = f + 1;
        }
    }

    if (!ok) return;   // unexpected layout: clean failure, no crash

    fused_voxel_attn<<<dim3(16384), dim3(256), 0, stream>>>(
        (const float*)d_in[idx[0]],                           // tok
        (const float*)d_in[idx[1]],                           // coords
        (const float*)d_in[idx[2]],                           // W1
        (const float*)d_in[idx[3]],                           // b1
        (const float*)d_in[idx[4]],                           // W2
        (const float*)d_in[idx[5]],  (const float*)d_in[idx[6]],   // Wq, bq
        (const float*)d_in[idx[7]],  (const float*)d_in[idx[8]],   // Wk, bk
        (const float*)d_in[idx[9]],  (const float*)d_in[idx[10]],  // Wv, bv
        (const float*)d_in[idx[11]], (const float*)d_in[idx[12]],  // Wo, bo
        (float*)d_out, out_size);
}